// Round 7
// baseline (267.822 us; speedup 1.0000x reference)
//
#include <hip/hip_runtime.h>
#include <hip/hip_bf16.h>

#define N_NODES 5000
#define N_EDGES 80000
#define HID_DIM 128
#define OUT_DIM 64
#define BATCH 8
#define M_ROWS 40000
#define NEG_SLOPE 0.2f
#define BUCKET 96   // fixed per-node capacity; deg~Poisson(16), P(>96)~0 (+20 sigma)

// R7: ATTRIBUTION ROUND. R6 structure (143.3us) with every kernel body repeated
// REP=4x idempotently (scatter atomics only on rep 0). dur = floor + 4K where
// 143.3 = floor + K  ->  K = (dur_R7 - 143.3)/3; inflated kernels > ~44us enter
// the top-5 profile with direct per-kernel durations. asm memory clobber between
// reps blocks cross-rep load CSE (loads must re-issue).

#define REP 4

typedef unsigned short ushort_t;
typedef unsigned int uint_t;
typedef __attribute__((ext_vector_type(8))) short short8;  // 8 bf16 = 4 VGPRs
typedef __attribute__((ext_vector_type(4))) float f32x4;

__device__ __forceinline__ float bf16_to_f32(ushort_t u) {
  return __uint_as_float(((uint_t)u) << 16);
}
__device__ __forceinline__ ushort_t f32_to_bf16(float f) {
  uint_t u = __float_as_uint(f);
  return (ushort_t)((u + 0x7FFF + ((u >> 16) & 1)) >> 16);  // RNE
}

struct __attribute__((aligned(8))) us4 { ushort_t x, y, z, w; };

// ws layout (R6)
#define OFF_BP1   0u          // 32 KB
#define OFF_BP2   32768u      // 16 KB
#define OFF_CMETA 49152u      // 2 floats (cl2, cr2)
#define OFF_CB    49184u      // 64 floats (c + b2)
#define OFF_Y     65536u      // 40000*64 bf16 = 5.12 MB
#define OFF_EY    5185536u    // 40000 float2 = 320 KB
#define OFF_W     5505536u    // 40000*64 bf16 = 5.12 MB
#define OFF_EL1   10625536u
#define OFF_ER1   10785536u
#define OFF_EL2   10945536u
#define OFF_ER2   11105536u
#define OFF_CNT   11265536u
#define OFF_SRCS  11285536u   // ends 13,205,536

// ---------------- setup: zero cnt + pack W1/W2 + c = b1@W2 metadata ----------------
__global__ __launch_bounds__(256) void zero_pack_kernel(const float* __restrict__ W1,
                                                        const float* __restrict__ W2,
                                                        const float* __restrict__ b1,
                                                        const float* __restrict__ b2,
                                                        const float* __restrict__ al2,
                                                        const float* __restrict__ ar2,
                                                        int* __restrict__ cnt,
                                                        ushort_t* __restrict__ Bp1,
                                                        ushort_t* __restrict__ Bp2,
                                                        float* __restrict__ cmeta,
                                                        float* __restrict__ cb) {
  for (int rep = 0; rep < REP; rep++) {
    int bid = blockIdx.x;
    if (bid < 20) {
      int i = bid * 256 + threadIdx.x;
      if (i < N_NODES) cnt[i] = 0;
    } else if (bid == 32) {
      int f = threadIdx.x;
      if (f < 64) {
        float c = 0.f;
#pragma unroll 8
        for (int k = 0; k < 128; k++) c += b1[k] * W2[(size_t)k * 64 + f];
        cb[f] = c + b2[f];
        float cl = c * al2[f], cr = c * ar2[f];
#pragma unroll
        for (int o = 32; o; o >>= 1) {
          cl += __shfl_xor(cl, o, 64);
          cr += __shfl_xor(cr, o, 64);
        }
        if (f == 0) { cmeta[0] = cl; cmeta[1] = cr; }
      }
    } else {
      int gid = (bid - 20) * 256 + threadIdx.x;  // 0..3071
      if (gid < 3072) {
        const float* W; ushort_t* Bp; int NC, idx;
        if (gid < 2048) { W = W1; Bp = Bp1; NC = 128; idx = gid; }
        else            { W = W2; Bp = Bp2; NC = 64;  idx = gid - 2048; }
        int l = idx & 63, tt = idx >> 6;
        int T = NC / 16;
        int kc = tt / T, t = tt % T;
        int col = t * 16 + (l & 15);
        int krow = kc * 32 + (l >> 4) * 8;
        short8 vv;
#pragma unroll
        for (int j = 0; j < 8; j++) vv[j] = (short)f32_to_bf16(W[(size_t)(krow + j) * NC + col]);
        *(short8*)(Bp + (size_t)idx * 8) = vv;
      }
    }
    asm volatile("" ::: "memory");
  }
}

// ---------------- fused gemm: z1 = x@W1 (LDS only) -> y = z1@W2; el1/er1 + ey; scatter ----
__global__ __launch_bounds__(256) void gemm_fused(const float* __restrict__ A,
                                                  const ushort_t* __restrict__ Bp1,
                                                  const ushort_t* __restrict__ Bp2,
                                                  const float* __restrict__ al1,
                                                  const float* __restrict__ ar1,
                                                  const float* __restrict__ al2,
                                                  const float* __restrict__ ar2,
                                                  float* __restrict__ el1,
                                                  float* __restrict__ er1,
                                                  ushort_t* __restrict__ y,
                                                  float2* __restrict__ ey,
                                                  const int* __restrict__ e_src,
                                                  const int* __restrict__ e_dst,
                                                  int* __restrict__ cnt,
                                                  int* __restrict__ srcs) {
  __shared__ ushort_t lds[64 * 128];  // 16 KB, z1 tile bf16, XOR-swizzled rows
  int wave = threadIdx.x >> 6, lane = threadIdx.x & 63;
  int q = lane >> 4, m = lane & 15;
  int r0 = blockIdx.x * 64 + wave * 16;

  for (int rep = 0; rep < REP; rep++) {
    // edge bucket-scatter prologue: REP 0 only (atomics not idempotent)
    if (rep == 0 && threadIdx.x < 128) {
      int i = blockIdx.x * 128 + threadIdx.x;
      int d = e_dst[i];
      int pos = atomicAdd(&cnt[d], 1);
      if (pos < BUCKET) srcs[d * BUCKET + pos] = e_src[i];  // clamp: structurally safe
    }

    // ---- stage 1: z1_tile = x_tile @ W1 (T=8) ----
    f32x4 acc[8];
#pragma unroll
    for (int t = 0; t < 8; t++)
#pragma unroll
      for (int i = 0; i < 4; i++) acc[t][i] = 0.f;
    const short8* B1 = (const short8*)Bp1;
    size_t arow = (size_t)(r0 + m) * 128;
#pragma unroll
    for (int kc = 0; kc < 4; kc++) {
      const float* Ap = A + arow + kc * 32 + q * 8;
      float4 v0 = *(const float4*)Ap;
      float4 v1 = *(const float4*)(Ap + 4);
      short8 af;
      af[0] = (short)f32_to_bf16(v0.x); af[1] = (short)f32_to_bf16(v0.y);
      af[2] = (short)f32_to_bf16(v0.z); af[3] = (short)f32_to_bf16(v0.w);
      af[4] = (short)f32_to_bf16(v1.x); af[5] = (short)f32_to_bf16(v1.y);
      af[6] = (short)f32_to_bf16(v1.z); af[7] = (short)f32_to_bf16(v1.w);
#pragma unroll
      for (int t = 0; t < 8; t++)
        acc[t] = __builtin_amdgcn_mfma_f32_16x16x32_bf16(af, B1[(kc * 8 + t) * 64 + lane], acc[t], 0, 0, 0);
    }
    // el1/er1 epilogue
    {
      float sl[4] = {0.f, 0.f, 0.f, 0.f}, sr[4] = {0.f, 0.f, 0.f, 0.f};
#pragma unroll
      for (int t = 0; t < 8; t++) {
        float alv = al1[t * 16 + m], arv = ar1[t * 16 + m];
#pragma unroll
        for (int i = 0; i < 4; i++) { sl[i] += acc[t][i] * alv; sr[i] += acc[t][i] * arv; }
      }
#pragma unroll
      for (int o = 1; o < 16; o <<= 1)
#pragma unroll
        for (int i = 0; i < 4; i++) {
          sl[i] += __shfl_xor(sl[i], o, 64);
          sr[i] += __shfl_xor(sr[i], o, 64);
        }
      if (m == 0)
#pragma unroll
        for (int i = 0; i < 4; i++) {
          el1[r0 + q * 4 + i] = sl[i];
          er1[r0 + q * 4 + i] = sr[i];
        }
    }
    // stage-1 -> LDS (bf16, RNE): row = q*4+i+wave*16, col = t*16+m; byte ^= (row&7)<<4
#pragma unroll
    for (int t = 0; t < 8; t++)
#pragma unroll
      for (int i = 0; i < 4; i++) {
        int row = q * 4 + i + wave * 16;
        int byte = row * 256 + (t * 16 + m) * 2;
        lds[(byte ^ ((row & 7) << 4)) >> 1] = f32_to_bf16(acc[t][i]);
      }
    __syncthreads();

    // ---- stage 2: y_tile = z1_tile(bf16) @ W2 (T=4) ----
    f32x4 acc2[4];
#pragma unroll
    for (int t = 0; t < 4; t++)
#pragma unroll
      for (int i = 0; i < 4; i++) acc2[t][i] = 0.f;
    const short8* B2 = (const short8*)Bp2;
    int row2 = wave * 16 + m;
#pragma unroll
    for (int kc = 0; kc < 4; kc++) {
      int byte = row2 * 256 + kc * 64 + q * 16;      // 16B-aligned; XOR keeps bits 0-3
      short8 af2 = *(const short8*)((const char*)lds + (byte ^ ((row2 & 7) << 4)));
#pragma unroll
      for (int t = 0; t < 4; t++)
        acc2[t] = __builtin_amdgcn_mfma_f32_16x16x32_bf16(af2, B2[(kc * 4 + t) * 64 + lane], acc2[t], 0, 0, 0);
    }
    // ey epilogue
    {
      float sl[4] = {0.f, 0.f, 0.f, 0.f}, sr[4] = {0.f, 0.f, 0.f, 0.f};
#pragma unroll
      for (int t = 0; t < 4; t++) {
        float alv = al2[t * 16 + m], arv = ar2[t * 16 + m];
#pragma unroll
        for (int i = 0; i < 4; i++) { sl[i] += acc2[t][i] * alv; sr[i] += acc2[t][i] * arv; }
      }
#pragma unroll
      for (int o = 1; o < 16; o <<= 1)
#pragma unroll
        for (int i = 0; i < 4; i++) {
          sl[i] += __shfl_xor(sl[i], o, 64);
          sr[i] += __shfl_xor(sr[i], o, 64);
        }
      if (m == 0)
#pragma unroll
        for (int i = 0; i < 4; i++) ey[r0 + q * 4 + i] = make_float2(sl[i], sr[i]);
    }
    // y store: row = r0 + q*4 + i, col = t*16 + m
#pragma unroll
    for (int t = 0; t < 4; t++)
#pragma unroll
      for (int i = 0; i < 4; i++)
        y[(size_t)(r0 + q * 4 + i) * 64 + t * 16 + m] = f32_to_bf16(acc2[t][i]);

    __syncthreads();  // WAR: next rep rewrites lds after stage-2 reads
    asm volatile("" ::: "memory");
  }
}

// ---------------- mid aggregation: w = A1·y ; el2/er2 = A1·ey + c·a (scalars) ----------
__global__ __launch_bounds__(256) void agg_mid(const ushort_t* __restrict__ y,
                                               const float2* __restrict__ ey,
                                               const float* __restrict__ el,
                                               const float* __restrict__ er,
                                               const int* __restrict__ cnt,
                                               const int* __restrict__ srcs,
                                               const float* __restrict__ cmeta,
                                               ushort_t* __restrict__ w,
                                               float* __restrict__ el2,
                                               float* __restrict__ er2) {
  int id = (threadIdx.x >> 6) * gridDim.x + blockIdx.x;  // gridDim%8==0: batch=XCD pairing
  int lane = threadIdx.x & 63;
  int g = lane >> 4, l16 = lane & 15;
  int b = id & 7, n = id >> 3;
  int deg = cnt[n]; if (deg > BUCKET) deg = BUCKET;
  int off0 = n * BUCKET;
  int rbase = b * N_NODES;
  float er_n = er[rbase + n];

  for (int rep = 0; rep < REP; rep++) {
    float acc[4] = {0.f, 0.f, 0.f, 0.f};
    float lsum = 0.f, sl2 = 0.f, sr2 = 0.f;

    for (int c = 0; c < deg; c += 64) {
      int j = c + lane;
      int s_my = 0;
      float w_my = 0.f;
      if (j < deg) {
        s_my = srcs[off0 + j];
        float e = el[rbase + s_my] + er_n;
        e = e > 0.f ? e : NEG_SLOPE * e;
        w_my = __expf(e);
        lsum += w_my;
        float2 ev = ey[rbase + s_my];
        sl2 += w_my * ev.x;
        sr2 += w_my * ev.y;
      }
      int cl = deg - c; if (cl > 64) cl = 64;
      for (int k0 = 0; k0 < cl; k0 += 16) {   // R5 4x-unrolled gather (MLP=4)
        float wk[4]; int sk[4];
#pragma unroll
        for (int u = 0; u < 4; u++) {
          int e_idx = k0 + u * 4 + g;
          wk[u] = __shfl(w_my, e_idx, 64);
          sk[u] = __shfl(s_my, e_idx, 64);
        }
        uint2 zw[4];
#pragma unroll
        for (int u = 0; u < 4; u++)
          zw[u] = *(const uint2*)(y + (size_t)(rbase + sk[u]) * 64 + l16 * 4);
#pragma unroll
        for (int u = 0; u < 4; u++) {
          acc[0] += wk[u] * bf16_to_f32((ushort_t)(zw[u].x & 0xFFFF));
          acc[1] += wk[u] * bf16_to_f32((ushort_t)(zw[u].x >> 16));
          acc[2] += wk[u] * bf16_to_f32((ushort_t)(zw[u].y & 0xFFFF));
          acc[3] += wk[u] * bf16_to_f32((ushort_t)(zw[u].y >> 16));
        }
      }
    }
#pragma unroll
    for (int j = 0; j < 4; j++) {
      acc[j] += __shfl_xor(acc[j], 16, 64);
      acc[j] += __shfl_xor(acc[j], 32, 64);
    }
    float sum = lsum;
#pragma unroll
    for (int o = 32; o; o >>= 1) {
      sum += __shfl_xor(sum, o, 64);
      sl2 += __shfl_xor(sl2, o, 64);
      sr2 += __shfl_xor(sr2, o, 64);
    }
    float inv = (deg > 0) ? 1.f / sum : 0.f;

    if (g == 0) {
      uint_t pk0 = (uint_t)f32_to_bf16(acc[0] * inv) | ((uint_t)f32_to_bf16(acc[1] * inv) << 16);
      uint_t pk1 = (uint_t)f32_to_bf16(acc[2] * inv) | ((uint_t)f32_to_bf16(acc[3] * inv) << 16);
      *(uint2*)(w + (size_t)(rbase + n) * 64 + l16 * 4) = make_uint2(pk0, pk1);
    }
    if (lane == 0) {
      el2[rbase + n] = sl2 * inv + cmeta[0];
      er2[rbase + n] = sr2 * inv + cmeta[1];
    }
    asm volatile("" ::: "memory");
  }
}

// ---------------- final aggregation: o = A2·w + cb, row softmax -> fp32 out ----------
__global__ __launch_bounds__(256) void agg_fin(const ushort_t* __restrict__ w,
                                               const float* __restrict__ el,
                                               const float* __restrict__ er,
                                               const float* __restrict__ cb,
                                               const int* __restrict__ cnt,
                                               const int* __restrict__ srcs,
                                               float* __restrict__ outp) {
  int id = (threadIdx.x >> 6) * gridDim.x + blockIdx.x;
  int lane = threadIdx.x & 63;
  int g = lane >> 4, l16 = lane & 15;
  int b = id & 7, n = id >> 3;
  int deg = cnt[n]; if (deg > BUCKET) deg = BUCKET;
  int off0 = n * BUCKET;
  int rbase = b * N_NODES;
  float er_n = er[rbase + n];

  for (int rep = 0; rep < REP; rep++) {
    float acc[4] = {0.f, 0.f, 0.f, 0.f};
    float lsum = 0.f;

    for (int c = 0; c < deg; c += 64) {
      int j = c + lane;
      int s_my = 0;
      float w_my = 0.f;
      if (j < deg) {
        s_my = srcs[off0 + j];
        float e = el[rbase + s_my] + er_n;
        e = e > 0.f ? e : NEG_SLOPE * e;
        w_my = __expf(e);
        lsum += w_my;
      }
      int cl = deg - c; if (cl > 64) cl = 64;
      for (int k0 = 0; k0 < cl; k0 += 16) {
        float wk[4]; int sk[4];
#pragma unroll
        for (int u = 0; u < 4; u++) {
          int e_idx = k0 + u * 4 + g;
          wk[u] = __shfl(w_my, e_idx, 64);
          sk[u] = __shfl(s_my, e_idx, 64);
        }
        uint2 zw[4];
#pragma unroll
        for (int u = 0; u < 4; u++)
          zw[u] = *(const uint2*)(w + (size_t)(rbase + sk[u]) * 64 + l16 * 4);
#pragma unroll
        for (int u = 0; u < 4; u++) {
          acc[0] += wk[u] * bf16_to_f32((ushort_t)(zw[u].x & 0xFFFF));
          acc[1] += wk[u] * bf16_to_f32((ushort_t)(zw[u].x >> 16));
          acc[2] += wk[u] * bf16_to_f32((ushort_t)(zw[u].y & 0xFFFF));
          acc[3] += wk[u] * bf16_to_f32((ushort_t)(zw[u].y >> 16));
        }
      }
    }
#pragma unroll
    for (int j = 0; j < 4; j++) {
      acc[j] += __shfl_xor(acc[j], 16, 64);
      acc[j] += __shfl_xor(acc[j], 32, 64);
    }
    float sum = lsum;
#pragma unroll
    for (int o = 32; o; o >>= 1) sum += __shfl_xor(sum, o, 64);
    float inv = (deg > 0) ? 1.f / sum : 0.f;

    float o[4];
#pragma unroll
    for (int j = 0; j < 4; j++) o[j] = acc[j] * inv + cb[l16 * 4 + j];
    float mm = fmaxf(fmaxf(o[0], o[1]), fmaxf(o[2], o[3]));
#pragma unroll
    for (int d = 1; d < 16; d <<= 1) mm = fmaxf(mm, __shfl_xor(mm, d, 64));
    float p0 = __expf(o[0] - mm), p1 = __expf(o[1] - mm);
    float p2 = __expf(o[2] - mm), p3 = __expf(o[3] - mm);
    float ss = p0 + p1 + p2 + p3;
#pragma unroll
    for (int d = 1; d < 16; d <<= 1) ss += __shfl_xor(ss, d, 64);
    if (g == 0) {
      float issv = 1.f / ss;
      *(float4*)(outp + (size_t)(rbase + n) * 64 + l16 * 4) =
          make_float4(p0 * issv, p1 * issv, p2 * issv, p3 * issv);
    }
    asm volatile("" ::: "memory");
  }
}

extern "C" void kernel_launch(void* const* d_in, const int* in_sizes, int n_in,
                              void* d_out, int out_size, void* d_ws, size_t ws_size,
                              hipStream_t stream) {
  const float* x   = (const float*)d_in[0];
  const float* W1  = (const float*)d_in[1];
  const float* al1 = (const float*)d_in[2];
  const float* ar1 = (const float*)d_in[3];
  const float* b1  = (const float*)d_in[4];
  const float* W2  = (const float*)d_in[5];
  const float* al2 = (const float*)d_in[6];
  const float* ar2 = (const float*)d_in[7];
  const float* b2  = (const float*)d_in[8];
  const int* src = (const int*)d_in[9];
  const int* dst = (const int*)d_in[10];

  char* base = (char*)d_ws;
  ushort_t* Bp1  = (ushort_t*)(base + OFF_BP1);
  ushort_t* Bp2  = (ushort_t*)(base + OFF_BP2);
  float*    cmeta= (float*)(base + OFF_CMETA);
  float*    cb   = (float*)(base + OFF_CB);
  ushort_t* y    = (ushort_t*)(base + OFF_Y);
  float2*   ey   = (float2*)(base + OFF_EY);
  ushort_t* w    = (ushort_t*)(base + OFF_W);
  float* el1 = (float*)(base + OFF_EL1);
  float* er1 = (float*)(base + OFF_ER1);
  float* el2 = (float*)(base + OFF_EL2);
  float* er2 = (float*)(base + OFF_ER2);
  int* cnt  = (int*)(base + OFF_CNT);
  int* srcs = (int*)(base + OFF_SRCS);

  // 1) setup: zero cnt + pack W1/W2 + c-metadata
  zero_pack_kernel<<<33, 256, 0, stream>>>(W1, W2, b1, b2, al2, ar2, cnt, Bp1, Bp2, cmeta, cb);

  // 2) fused GEMM: x@W1 -> LDS -> @W2 = y; el1/er1 + ey; edge scatter
  gemm_fused<<<M_ROWS / 64, 256, 0, stream>>>(x, Bp1, Bp2, al1, ar1, al2, ar2,
                                              el1, er1, y, ey, src, dst, cnt, srcs);

  // 3) mid aggregation: w = A1·y ; el2/er2
  agg_mid<<<M_ROWS / 4, 256, 0, stream>>>(y, ey, el1, er1, cnt, srcs, cmeta, w, el2, er2);

  // 4) final aggregation + row softmax
  agg_fin<<<M_ROWS / 4, 256, 0, stream>>>(w, el2, er2, cb, cnt, srcs, (float*)d_out);
}

// Round 8
// 146.762 us; speedup vs baseline: 1.8249x; 1.8249x over previous
//
#include <hip/hip_runtime.h>
#include <hip/hip_bf16.h>

#define N_NODES 5000
#define N_EDGES 80000
#define HID_DIM 128
#define OUT_DIM 64
#define BATCH 8
#define M_ROWS 40000
#define NEG_SLOPE 0.2f
#define BUCKET 96   // fixed per-node capacity; deg~Poisson(16), P(>96)~0 (+20 sigma)

// R8: dispatch-count reduction (floor ~102us of 143 total; ~8-11us/launch).
// Setup kernel eliminated: cnt zero -> hipMemsetAsync; W-pack -> per-block LDS
// inside gemm_fused (L2-hot, ~0.2us aggregate); cb/cmeta -> gemm_fused block 0.
// 4 enqueues total: memset(cnt) + gemm_fused + agg_mid + agg_fin.
// agg kernels byte-identical to R6 (proven 143.3us / absmax 3.7e-4).

typedef unsigned short ushort_t;
typedef unsigned int uint_t;
typedef __attribute__((ext_vector_type(8))) short short8;  // 8 bf16 = 4 VGPRs
typedef __attribute__((ext_vector_type(4))) float f32x4;

__device__ __forceinline__ float bf16_to_f32(ushort_t u) {
  return __uint_as_float(((uint_t)u) << 16);
}
__device__ __forceinline__ ushort_t f32_to_bf16(float f) {
  uint_t u = __float_as_uint(f);
  return (ushort_t)((u + 0x7FFF + ((u >> 16) & 1)) >> 16);  // RNE
}

// ws layout (R8)
#define OFF_CMETA 49152u      // 2 floats (cl2, cr2)
#define OFF_CB    49184u      // 64 floats (c + b2)
#define OFF_Y     65536u      // 40000*64 bf16 = 5.12 MB
#define OFF_EY    5185536u    // 40000 float2 = 320 KB
#define OFF_W     5505536u    // 40000*64 bf16 = 5.12 MB
#define OFF_EL1   10625536u
#define OFF_ER1   10785536u
#define OFF_EL2   10945536u
#define OFF_ER2   11105536u
#define OFF_CNT   11265536u   // 5000 ints (memset target)
#define OFF_SRCS  11285536u   // 5000*96 ints, ends 13,205,536

// ---------------- fused gemm: pack W (LDS) + scatter + x@W1 -> LDS -> @W2 = y ------------
__global__ __launch_bounds__(256) void gemm_fused(const float* __restrict__ A,
                                                  const float* __restrict__ W1,
                                                  const float* __restrict__ W2,
                                                  const float* __restrict__ b1,
                                                  const float* __restrict__ b2,
                                                  const float* __restrict__ al1,
                                                  const float* __restrict__ ar1,
                                                  const float* __restrict__ al2,
                                                  const float* __restrict__ ar2,
                                                  float* __restrict__ el1,
                                                  float* __restrict__ er1,
                                                  ushort_t* __restrict__ y,
                                                  float2* __restrict__ ey,
                                                  const int* __restrict__ e_src,
                                                  const int* __restrict__ e_dst,
                                                  int* __restrict__ cnt,
                                                  int* __restrict__ srcs,
                                                  float* __restrict__ cmeta,
                                                  float* __restrict__ cb) {
  __shared__ ushort_t ldsB1[2048 * 8];   // 32 KB: W1 fragments (idx 0..2047)
  __shared__ ushort_t ldsB2[1024 * 8];   // 16 KB: W2 fragments (idx 0..1023)
  __shared__ ushort_t lds[64 * 128];     // 16 KB: z1 tile bf16, XOR-swizzled rows
  int wave = threadIdx.x >> 6, lane = threadIdx.x & 63;
  int q = lane >> 4, m = lane & 15;
  int r0 = blockIdx.x * 64 + wave * 16;

  // ---- prologue A: edge bucket-scatter (gridDim=625 x 128 = 80000 exactly) ----
  if (threadIdx.x < 128) {
    int i = blockIdx.x * 128 + threadIdx.x;
    int d = e_dst[i];
    int pos = atomicAdd(&cnt[d], 1);
    if (pos < BUCKET) srcs[d * BUCKET + pos] = e_src[i];  // clamp: structurally safe
  }

  // ---- prologue B: pack W1/W2 -> LDS fragments (same mapping as proven setup kernel) ----
  for (int it = 0; it < 12; it++) {
    int gid = it * 256 + threadIdx.x;  // 0..3071
    const float* W; ushort_t* Bp; int NC, idx;
    if (gid < 2048) { W = W1; Bp = ldsB1; NC = 128; idx = gid; }
    else            { W = W2; Bp = ldsB2; NC = 64;  idx = gid - 2048; }
    int l = idx & 63, tt = idx >> 6;
    int T = NC / 16;
    int kc = tt / T, t = tt % T;
    int col = t * 16 + (l & 15);
    int krow = kc * 32 + (l >> 4) * 8;
    short8 vv;
#pragma unroll
    for (int j = 0; j < 8; j++) vv[j] = (short)f32_to_bf16(W[(size_t)(krow + j) * NC + col]);
    *(short8*)(Bp + (size_t)idx * 8) = vv;
  }

  // ---- prologue C (block 0 only): cb = b1@W2 + b2 ; cmeta = (c·al2, c·ar2) sums ----
  if (blockIdx.x == 0 && threadIdx.x < 64) {
    int f = threadIdx.x;
    float c = 0.f;
#pragma unroll 8
    for (int k = 0; k < 128; k++) c += b1[k] * W2[(size_t)k * 64 + f];
    cb[f] = c + b2[f];
    float cl = c * al2[f], cr = c * ar2[f];
#pragma unroll
    for (int o = 32; o; o >>= 1) {
      cl += __shfl_xor(cl, o, 64);
      cr += __shfl_xor(cr, o, 64);
    }
    if (f == 0) { cmeta[0] = cl; cmeta[1] = cr; }
  }
  __syncthreads();

  // ---- stage 1: z1_tile = x_tile @ W1 (T=8) ----
  f32x4 acc[8];
#pragma unroll
  for (int t = 0; t < 8; t++)
#pragma unroll
    for (int i = 0; i < 4; i++) acc[t][i] = 0.f;
  const short8* B1 = (const short8*)ldsB1;
  size_t arow = (size_t)(r0 + m) * 128;
#pragma unroll
  for (int kc = 0; kc < 4; kc++) {
    const float* Ap = A + arow + kc * 32 + q * 8;
    float4 v0 = *(const float4*)Ap;
    float4 v1 = *(const float4*)(Ap + 4);
    short8 af;
    af[0] = (short)f32_to_bf16(v0.x); af[1] = (short)f32_to_bf16(v0.y);
    af[2] = (short)f32_to_bf16(v0.z); af[3] = (short)f32_to_bf16(v0.w);
    af[4] = (short)f32_to_bf16(v1.x); af[5] = (short)f32_to_bf16(v1.y);
    af[6] = (short)f32_to_bf16(v1.z); af[7] = (short)f32_to_bf16(v1.w);
#pragma unroll
    for (int t = 0; t < 8; t++)
      acc[t] = __builtin_amdgcn_mfma_f32_16x16x32_bf16(af, B1[(kc * 8 + t) * 64 + lane], acc[t], 0, 0, 0);
  }
  // el1/er1 epilogue (fp32 acc, reduce over 16 m-lanes) — proven pattern
  {
    float sl[4] = {0.f, 0.f, 0.f, 0.f}, sr[4] = {0.f, 0.f, 0.f, 0.f};
#pragma unroll
    for (int t = 0; t < 8; t++) {
      float alv = al1[t * 16 + m], arv = ar1[t * 16 + m];
#pragma unroll
      for (int i = 0; i < 4; i++) { sl[i] += acc[t][i] * alv; sr[i] += acc[t][i] * arv; }
    }
#pragma unroll
    for (int o = 1; o < 16; o <<= 1)
#pragma unroll
      for (int i = 0; i < 4; i++) {
        sl[i] += __shfl_xor(sl[i], o, 64);
        sr[i] += __shfl_xor(sr[i], o, 64);
      }
    if (m == 0)
#pragma unroll
      for (int i = 0; i < 4; i++) {
        el1[r0 + q * 4 + i] = sl[i];
        er1[r0 + q * 4 + i] = sr[i];
      }
  }
  // stage-1 -> LDS (bf16, RNE): row = q*4+i+wave*16, col = t*16+m; byte ^= (row&7)<<4
#pragma unroll
  for (int t = 0; t < 8; t++)
#pragma unroll
    for (int i = 0; i < 4; i++) {
      int row = q * 4 + i + wave * 16;
      int byte = row * 256 + (t * 16 + m) * 2;
      lds[(byte ^ ((row & 7) << 4)) >> 1] = f32_to_bf16(acc[t][i]);
    }
  __syncthreads();

  // ---- stage 2: y_tile = z1_tile(bf16) @ W2 (T=4) ----
  f32x4 acc2[4];
#pragma unroll
  for (int t = 0; t < 4; t++)
#pragma unroll
    for (int i = 0; i < 4; i++) acc2[t][i] = 0.f;
  const short8* B2 = (const short8*)ldsB2;
  int row2 = wave * 16 + m;
#pragma unroll
  for (int kc = 0; kc < 4; kc++) {
    int byte = row2 * 256 + kc * 64 + q * 16;      // 16B-aligned; XOR keeps bits 0-3
    short8 af2 = *(const short8*)((const char*)lds + (byte ^ ((row2 & 7) << 4)));
#pragma unroll
    for (int t = 0; t < 4; t++)
      acc2[t] = __builtin_amdgcn_mfma_f32_16x16x32_bf16(af2, B2[(kc * 4 + t) * 64 + lane], acc2[t], 0, 0, 0);
  }
  // ey epilogue (y·al2, y·ar2 per row, fp32 pre-rounding)
  {
    float sl[4] = {0.f, 0.f, 0.f, 0.f}, sr[4] = {0.f, 0.f, 0.f, 0.f};
#pragma unroll
    for (int t = 0; t < 4; t++) {
      float alv = al2[t * 16 + m], arv = ar2[t * 16 + m];
#pragma unroll
      for (int i = 0; i < 4; i++) { sl[i] += acc2[t][i] * alv; sr[i] += acc2[t][i] * arv; }
    }
#pragma unroll
    for (int o = 1; o < 16; o <<= 1)
#pragma unroll
      for (int i = 0; i < 4; i++) {
        sl[i] += __shfl_xor(sl[i], o, 64);
        sr[i] += __shfl_xor(sr[i], o, 64);
      }
    if (m == 0)
#pragma unroll
      for (int i = 0; i < 4; i++) ey[r0 + q * 4 + i] = make_float2(sl[i], sr[i]);
  }
  // y store: row = r0 + q*4 + i, col = t*16 + m (m89-verified layout)
#pragma unroll
  for (int t = 0; t < 4; t++)
#pragma unroll
    for (int i = 0; i < 4; i++)
      y[(size_t)(r0 + q * 4 + i) * 64 + t * 16 + m] = f32_to_bf16(acc2[t][i]);
}

// ---------------- mid aggregation: w = A1·y ; el2/er2 = A1·ey + c·a (scalars) ----------
__global__ __launch_bounds__(256) void agg_mid(const ushort_t* __restrict__ y,
                                               const float2* __restrict__ ey,
                                               const float* __restrict__ el,
                                               const float* __restrict__ er,
                                               const int* __restrict__ cnt,
                                               const int* __restrict__ srcs,
                                               const float* __restrict__ cmeta,
                                               ushort_t* __restrict__ w,
                                               float* __restrict__ el2,
                                               float* __restrict__ er2) {
  int id = (threadIdx.x >> 6) * gridDim.x + blockIdx.x;  // gridDim%8==0: batch=XCD pairing
  int lane = threadIdx.x & 63;
  int g = lane >> 4, l16 = lane & 15;
  int b = id & 7, n = id >> 3;
  int deg = cnt[n]; if (deg > BUCKET) deg = BUCKET;
  int off0 = n * BUCKET;
  int rbase = b * N_NODES;
  float er_n = er[rbase + n];

  float acc[4] = {0.f, 0.f, 0.f, 0.f};
  float lsum = 0.f, sl2 = 0.f, sr2 = 0.f;

  for (int c = 0; c < deg; c += 64) {
    int j = c + lane;
    int s_my = 0;
    float w_my = 0.f;
    if (j < deg) {
      s_my = srcs[off0 + j];
      float e = el[rbase + s_my] + er_n;
      e = e > 0.f ? e : NEG_SLOPE * e;
      w_my = __expf(e);
      lsum += w_my;
      float2 ev = ey[rbase + s_my];
      sl2 += w_my * ev.x;
      sr2 += w_my * ev.y;
    }
    int cl = deg - c; if (cl > 64) cl = 64;
    for (int k0 = 0; k0 < cl; k0 += 16) {   // R5 4x-unrolled gather (MLP=4)
      float wk[4]; int sk[4];
#pragma unroll
      for (int u = 0; u < 4; u++) {
        int e_idx = k0 + u * 4 + g;
        wk[u] = __shfl(w_my, e_idx, 64);
        sk[u] = __shfl(s_my, e_idx, 64);
      }
      uint2 zw[4];
#pragma unroll
      for (int u = 0; u < 4; u++)
        zw[u] = *(const uint2*)(y + (size_t)(rbase + sk[u]) * 64 + l16 * 4);
#pragma unroll
      for (int u = 0; u < 4; u++) {
        acc[0] += wk[u] * bf16_to_f32((ushort_t)(zw[u].x & 0xFFFF));
        acc[1] += wk[u] * bf16_to_f32((ushort_t)(zw[u].x >> 16));
        acc[2] += wk[u] * bf16_to_f32((ushort_t)(zw[u].y & 0xFFFF));
        acc[3] += wk[u] * bf16_to_f32((ushort_t)(zw[u].y >> 16));
      }
    }
  }
#pragma unroll
  for (int j = 0; j < 4; j++) {
    acc[j] += __shfl_xor(acc[j], 16, 64);
    acc[j] += __shfl_xor(acc[j], 32, 64);
  }
  float sum = lsum;
#pragma unroll
  for (int o = 32; o; o >>= 1) {
    sum += __shfl_xor(sum, o, 64);
    sl2 += __shfl_xor(sl2, o, 64);
    sr2 += __shfl_xor(sr2, o, 64);
  }
  float inv = (deg > 0) ? 1.f / sum : 0.f;

  if (g == 0) {
    uint_t pk0 = (uint_t)f32_to_bf16(acc[0] * inv) | ((uint_t)f32_to_bf16(acc[1] * inv) << 16);
    uint_t pk1 = (uint_t)f32_to_bf16(acc[2] * inv) | ((uint_t)f32_to_bf16(acc[3] * inv) << 16);
    *(uint2*)(w + (size_t)(rbase + n) * 64 + l16 * 4) = make_uint2(pk0, pk1);
  }
  if (lane == 0) {
    el2[rbase + n] = sl2 * inv + cmeta[0];
    er2[rbase + n] = sr2 * inv + cmeta[1];
  }
}

// ---------------- final aggregation: o = A2·w + cb, row softmax -> fp32 out ----------
__global__ __launch_bounds__(256) void agg_fin(const ushort_t* __restrict__ w,
                                               const float* __restrict__ el,
                                               const float* __restrict__ er,
                                               const float* __restrict__ cb,
                                               const int* __restrict__ cnt,
                                               const int* __restrict__ srcs,
                                               float* __restrict__ outp) {
  int id = (threadIdx.x >> 6) * gridDim.x + blockIdx.x;
  int lane = threadIdx.x & 63;
  int g = lane >> 4, l16 = lane & 15;
  int b = id & 7, n = id >> 3;
  int deg = cnt[n]; if (deg > BUCKET) deg = BUCKET;
  int off0 = n * BUCKET;
  int rbase = b * N_NODES;
  float er_n = er[rbase + n];

  float acc[4] = {0.f, 0.f, 0.f, 0.f};
  float lsum = 0.f;

  for (int c = 0; c < deg; c += 64) {
    int j = c + lane;
    int s_my = 0;
    float w_my = 0.f;
    if (j < deg) {
      s_my = srcs[off0 + j];
      float e = el[rbase + s_my] + er_n;
      e = e > 0.f ? e : NEG_SLOPE * e;
      w_my = __expf(e);
      lsum += w_my;
    }
    int cl = deg - c; if (cl > 64) cl = 64;
    for (int k0 = 0; k0 < cl; k0 += 16) {
      float wk[4]; int sk[4];
#pragma unroll
      for (int u = 0; u < 4; u++) {
        int e_idx = k0 + u * 4 + g;
        wk[u] = __shfl(w_my, e_idx, 64);
        sk[u] = __shfl(s_my, e_idx, 64);
      }
      uint2 zw[4];
#pragma unroll
      for (int u = 0; u < 4; u++)
        zw[u] = *(const uint2*)(w + (size_t)(rbase + sk[u]) * 64 + l16 * 4);
#pragma unroll
      for (int u = 0; u < 4; u++) {
        acc[0] += wk[u] * bf16_to_f32((ushort_t)(zw[u].x & 0xFFFF));
        acc[1] += wk[u] * bf16_to_f32((ushort_t)(zw[u].x >> 16));
        acc[2] += wk[u] * bf16_to_f32((ushort_t)(zw[u].y & 0xFFFF));
        acc[3] += wk[u] * bf16_to_f32((ushort_t)(zw[u].y >> 16));
      }
    }
  }
#pragma unroll
  for (int j = 0; j < 4; j++) {
    acc[j] += __shfl_xor(acc[j], 16, 64);
    acc[j] += __shfl_xor(acc[j], 32, 64);
  }
  float sum = lsum;
#pragma unroll
  for (int o = 32; o; o >>= 1) sum += __shfl_xor(sum, o, 64);
  float inv = (deg > 0) ? 1.f / sum : 0.f;

  float o[4];
#pragma unroll
  for (int j = 0; j < 4; j++) o[j] = acc[j] * inv + cb[l16 * 4 + j];
  float mm = fmaxf(fmaxf(o[0], o[1]), fmaxf(o[2], o[3]));
#pragma unroll
  for (int d = 1; d < 16; d <<= 1) mm = fmaxf(mm, __shfl_xor(mm, d, 64));
  float p0 = __expf(o[0] - mm), p1 = __expf(o[1] - mm);
  float p2 = __expf(o[2] - mm), p3 = __expf(o[3] - mm);
  float ss = p0 + p1 + p2 + p3;
#pragma unroll
  for (int d = 1; d < 16; d <<= 1) ss += __shfl_xor(ss, d, 64);
  if (g == 0) {
    float issv = 1.f / ss;
    *(float4*)(outp + (size_t)(rbase + n) * 64 + l16 * 4) =
        make_float4(p0 * issv, p1 * issv, p2 * issv, p3 * issv);
  }
}

extern "C" void kernel_launch(void* const* d_in, const int* in_sizes, int n_in,
                              void* d_out, int out_size, void* d_ws, size_t ws_size,
                              hipStream_t stream) {
  const float* x   = (const float*)d_in[0];
  const float* W1  = (const float*)d_in[1];
  const float* al1 = (const float*)d_in[2];
  const float* ar1 = (const float*)d_in[3];
  const float* b1  = (const float*)d_in[4];
  const float* W2  = (const float*)d_in[5];
  const float* al2 = (const float*)d_in[6];
  const float* ar2 = (const float*)d_in[7];
  const float* b2  = (const float*)d_in[8];
  const int* src = (const int*)d_in[9];
  const int* dst = (const int*)d_in[10];

  char* base = (char*)d_ws;
  float*    cmeta= (float*)(base + OFF_CMETA);
  float*    cb   = (float*)(base + OFF_CB);
  ushort_t* y    = (ushort_t*)(base + OFF_Y);
  float2*   ey   = (float2*)(base + OFF_EY);
  ushort_t* w    = (ushort_t*)(base + OFF_W);
  float* el1 = (float*)(base + OFF_EL1);
  float* er1 = (float*)(base + OFF_ER1);
  float* el2 = (float*)(base + OFF_EL2);
  float* er2 = (float*)(base + OFF_ER2);
  int* cnt  = (int*)(base + OFF_CNT);
  int* srcs = (int*)(base + OFF_SRCS);

  // 1) zero cnt (replaces the setup dispatch)
  hipMemsetAsync(cnt, 0, N_NODES * sizeof(int), stream);

  // 2) fused GEMM: pack W (LDS) + cb/cmeta (block 0) + scatter + x@W1 -> LDS -> @W2 = y
  gemm_fused<<<M_ROWS / 64, 256, 0, stream>>>(x, W1, W2, b1, b2, al1, ar1, al2, ar2,
                                              el1, er1, y, ey, src, dst, cnt, srcs,
                                              cmeta, cb);

  // 3) mid aggregation: w = A1·y ; el2/er2
  agg_mid<<<M_ROWS / 4, 256, 0, stream>>>(y, ey, el1, er1, cnt, srcs, cmeta, w, el2, er2);

  // 4) final aggregation + row softmax
  agg_fin<<<M_ROWS / 4, 256, 0, stream>>>(w, el2, er2, cb, cnt, srcs, (float*)d_out);
}